// Round 14
// baseline (636.629 us; speedup 1.0000x reference)
//
#include <hip/hip_runtime.h>
#include <hip/hip_bf16.h>

#define H 128
#define LATD 32

typedef __attribute__((ext_vector_type(8))) _Float16 half8t;        // 8 fp16
typedef __attribute__((ext_vector_type(4))) _Float16 half4t;        // 4 fp16
typedef __attribute__((ext_vector_type(2))) _Float16 half2t;        // 2 fp16
typedef __attribute__((ext_vector_type(8))) unsigned short u16x8;   // 16B copy unit
typedef __attribute__((ext_vector_type(4))) float f32x4;

// packed-weight region offsets (u16 elements)
#define OFF_W2  12288     // 3 x [4kt][8ct][64][8]   (We2)
#define OFF_PROJ 61440    // 3 x [4kt][16ct][64][8]  ([We1_src | We1_dst] 128x256)
#define OFF_H1  159744    // 3 x [8kt][8ct][64][8]   (Wh1)
#define OFF_H2  258048    // 3 x [4kt][8ct][64][8]   (Wh2)
#define OFF_KV  307200    // 1 x [4kt][16ct][64][8]  ([Wk | Wv] 128x256)
#define OFF_RBF16 339968  // 3 x [8ct][64][4]        (We1 rows 256..271, K=16 frags)
#define WP_TOTAL 346112

// silu via native rcp (avoids IEEE div sequence)
__device__ __forceinline__ float silu_f(float x) {
  return x * __builtin_amdgcn_rcpf(1.0f + __expf(-x));
}
__device__ __forceinline__ unsigned short f16u(float x) {
  _Float16 hh = (_Float16)x;
  return *(unsigned short*)&hh;
}

// pad coords (A,3) -> float4 so each gather is a single aligned line
__global__ void k_pad4(const float* __restrict__ coords, float4* __restrict__ c4, int A) {
  int a = blockIdx.x * blockDim.x + threadIdx.x;
  if (a >= A) return;
  c4[a] = make_float4(coords[3*a], coords[3*a+1], coords[3*a+2], 0.f);
}

// fused: distance + dst histogram (cnt must be zeroed before launch)
__global__ void k_dist(const float4* __restrict__ c4,
                       const int* __restrict__ esrc, const int* __restrict__ edst,
                       float* __restrict__ dbuf, int* __restrict__ cnt, int E) {
  int e = blockIdx.x * blockDim.x + threadIdx.x;
  if (e >= E) return;
  int s = esrc[e], t = edst[e];
  float4 a = c4[s], b = c4[t];
  float dx = a.x - b.x, dy = a.y - b.y, dz = a.z - b.z;
  dbuf[e] = sqrtf(dx*dx + dy*dy + dz*dz);
  atomicAdd(&cnt[t], 1);
}

__global__ __launch_bounds__(1024) void k_scanA(const int* __restrict__ cnt,
                                                int* __restrict__ cursor,
                                                int* __restrict__ bsum, int A) {
  __shared__ int buf[1024];
  int tid = threadIdx.x;
  int i = blockIdx.x * 1024 + tid;
  int v = (i < A) ? cnt[i] : 0;
  buf[tid] = v;
  __syncthreads();
  #pragma unroll
  for (int off = 1; off < 1024; off <<= 1) {
    int nv = (tid >= off) ? buf[tid - off] : 0;
    __syncthreads();
    buf[tid] += nv;
    __syncthreads();
  }
  if (i < A) cursor[i] = buf[tid] - v;   // exclusive within chunk
  if (tid == 1023) bsum[blockIdx.x] = buf[1023];
}

__global__ void k_scanB(int* __restrict__ bsum, int nb) {
  int lane = threadIdx.x;                 // one wave, nb <= 64
  int v = (lane < nb) ? bsum[lane] : 0;
  int s = v;
  #pragma unroll
  for (int off = 1; off < 64; off <<= 1) {
    int nv = __shfl_up(s, off);
    if (lane >= off) s += nv;
  }
  if (lane < nb) bsum[lane] = s - v;      // exclusive
}

// scatter with fused scanC: final position = local-scan + chunk offset
__global__ void k_scatter(const int* __restrict__ edst, int* __restrict__ cursor,
                          const int* __restrict__ bsum,
                          int* __restrict__ eperm, int E) {
  int e = blockIdx.x * blockDim.x + threadIdx.x;
  if (e >= E) return;
  int t = edst[e];
  int p = atomicAdd(&cursor[t], 1) + bsum[t >> 10];
  eperm[p] = e;
}

// ---------------- weight packing into per-lane-contiguous fragments --------
__global__ void k_pack(const float* __restrict__ We1, const float* __restrict__ We2,
                       const float* __restrict__ Wh1, const float* __restrict__ Wh2,
                       const float* __restrict__ Wk,  const float* __restrict__ Wv,
                       unsigned short* __restrict__ wp) {
  int t = blockIdx.x * blockDim.x + threadIdx.x;
  if (t >= WP_TOTAL) return;
  if (t < OFF_W2) {                      // legacy region (unused)
    wp[t] = 0;
  } else if (t < OFF_PROJ) {             // We2 128x128
    int u = t - OFF_W2; int layer = u / 16384, idx = u % 16384;
    int i = idx & 7, lane = (idx >> 3) & 63, ct = (idx >> 9) & 7, kt = idx >> 12;
    int k = kt * 32 + (lane >> 4) * 8 + i, c = ct * 16 + (lane & 15);
    const float* src = We2 + (size_t)layer * 128 * H;
    wp[t] = f16u(src[(size_t)k * H + c]);
  } else if (t < OFF_H1) {               // proj: [We1_src | We1_dst] 128x256
    int u = t - OFF_PROJ; int layer = u / 32768, idx = u % 32768;
    int i = idx & 7, lane = (idx >> 3) & 63, ct = (idx >> 9) & 15, kt = idx >> 13;
    int k = kt * 32 + (lane >> 4) * 8 + i, c = ct * 16 + (lane & 15);
    const float* src = We1 + (size_t)layer * 272 * H;
    float v = (c < 128) ? src[(size_t)k * H + c] : src[(size_t)(128 + k) * H + (c - 128)];
    wp[t] = f16u(v);
  } else if (t < OFF_H2) {               // Wh1 256x128
    int u = t - OFF_H1; int layer = u / 32768, idx = u % 32768;
    int i = idx & 7, lane = (idx >> 3) & 63, ct = (idx >> 9) & 7, kt = idx >> 12;
    int k = kt * 32 + (lane >> 4) * 8 + i, c = ct * 16 + (lane & 15);
    const float* src = Wh1 + (size_t)layer * 256 * H;
    wp[t] = f16u(src[(size_t)k * H + c]);
  } else if (t < OFF_KV) {               // Wh2 128x128
    int u = t - OFF_H2; int layer = u / 16384, idx = u % 16384;
    int i = idx & 7, lane = (idx >> 3) & 63, ct = (idx >> 9) & 7, kt = idx >> 12;
    int k = kt * 32 + (lane >> 4) * 8 + i, c = ct * 16 + (lane & 15);
    const float* src = Wh2 + (size_t)layer * 128 * H;
    wp[t] = f16u(src[(size_t)k * H + c]);
  } else if (t < OFF_RBF16) {            // [Wk | Wv] 128x256
    int idx = t - OFF_KV;
    int i = idx & 7, lane = (idx >> 3) & 63, ct = (idx >> 9) & 15, kt = idx >> 13;
    int k = kt * 32 + (lane >> 4) * 8 + i, c = ct * 16 + (lane & 15);
    float v = (c < 128) ? Wk[(size_t)k * H + c] : Wv[(size_t)k * H + (c - 128)];
    wp[t] = f16u(v);
  } else {                               // rbf16: We1 rows 256..271 as K=16 A-frags
    int u = t - OFF_RBF16; int layer = u / 2048, idx = u % 2048;
    int i = idx & 3, lane = (idx >> 2) & 63, ct = idx >> 8;
    int k = (lane >> 4) * 4 + i;
    int c = ct * 16 + (lane & 15);
    const float* src = We1 + (size_t)layer * 272 * H;
    wp[t] = f16u(src[(size_t)(256 + k) * H + c]);
  }
}

// ---------------- fused init: embed-init + starts + agg-zero + proj(l0) ----
// NOTE: fp16 hb is the master h (no f32 copy).
#define PS2 136   // LDS hb stride (fp16)

__global__ __launch_bounds__(256) void k_init_proj(
    const float* __restrict__ atom_embed, const float* __restrict__ residue_embed,
    const int* __restrict__ atype, const int* __restrict__ ridx,
    const int* __restrict__ rtype,
    unsigned short* __restrict__ hb,
    int* __restrict__ starts, float* __restrict__ agg,
    const unsigned short* __restrict__ Wp, unsigned short* __restrict__ Ph, int A) {
  __shared__ __align__(16) unsigned short Xp[64 * PS2];   // 17408 B
  const int tid = threadIdx.x;
  const int a0 = blockIdx.x * 64;
  {
    const int r = tid >> 2, qt = tid & 3;
    int a = a0 + r;
    int ac = (a < A) ? a : (A - 1);
    int ri = ridx[ac];
    const float* ae = atom_embed + (size_t)atype[ac] * H + qt * 32;
    const float* re = residue_embed + (size_t)rtype[ri] * H + qt * 32;
    if (a < A) {
      if (qt == 0 && (a == 0 || ridx[a - 1] != ri)) starts[ri] = a;
      float4 z = {0.f, 0.f, 0.f, 0.f};
      float4* az = (float4*)(agg + (size_t)a * H + qt * 32);
      #pragma unroll
      for (int i = 0; i < 8; ++i) az[i] = z;
      #pragma unroll
      for (int j = 0; j < 32; ++j) {
        float v = ae[j] + re[j];
        unsigned short u = f16u(v);
        hb[(size_t)a * H + qt * 32 + j] = u;
        Xp[r * PS2 + qt * 32 + j] = u;
      }
    } else {
      #pragma unroll
      for (int j = 0; j < 32; ++j)
        Xp[r * PS2 + qt * 32 + j] = f16u(ae[j] + re[j]);
    }
  }
  __syncthreads();
  const int l = tid & 63, wv = tid >> 6;
  const int lr = l & 15, lk = (l >> 4) * 8;
  f32x4 acc[4][4] = {};
  #pragma unroll
  for (int kt = 0; kt < 4; ++kt) {
    half8t a[4], b[4];
    #pragma unroll
    for (int rt = 0; rt < 4; ++rt)
      a[rt] = *(const half8t*)&Xp[(rt * 16 + lr) * PS2 + kt * 32 + lk];
    #pragma unroll
    for (int ci = 0; ci < 4; ++ci)
      b[ci] = *(const half8t*)&Wp[(((size_t)kt * 16 + wv * 4 + ci) * 64 + l) * 8];
    #pragma unroll
    for (int rt = 0; rt < 4; ++rt)
      #pragma unroll
      for (int ci = 0; ci < 4; ++ci)
        acc[rt][ci] = __builtin_amdgcn_mfma_f32_16x16x32_f16(a[rt], b[ci], acc[rt][ci], 0, 0, 0);
  }
  #pragma unroll
  for (int rt = 0; rt < 4; ++rt)
    #pragma unroll
    for (int ci = 0; ci < 4; ++ci) {
      int col = (wv * 4 + ci) * 16 + lr;
      #pragma unroll
      for (int rr = 0; rr < 4; ++rr) {
        int row = a0 + rt * 16 + (l >> 4) * 4 + rr;
        if (row < A) Ph[(size_t)row * 256 + col] = f16u(acc[rt][ci][rr]);
      }
    }
}

// ---------------- edge kernel (r11 config + identity-MFMA acc init) --------
#define ES 136    // shared stride (fp16): 272B/row, 16B-aligned

__global__ __launch_bounds__(256, 8) void k_edge_mfma(
    const unsigned short* __restrict__ Ph, const float* __restrict__ dbuf,
    const int* __restrict__ esrc, const int* __restrict__ edst,
    const int* __restrict__ eperm,
    const unsigned short* __restrict__ Wr16, const float* __restrict__ be1,
    const unsigned short* __restrict__ W2p, const float* __restrict__ be2,
    float* __restrict__ agg, int E) {
  __shared__ __align__(16) unsigned short SH[64 * ES];  // 17408 B (Psum/M1/M2h)
  __shared__ int dstv[64];
  __shared__ float dval[64];

  const int tid = threadIdx.x;
  const int e0 = blockIdx.x * 64;
  const int l = tid & 63, wv = tid >> 6;
  const int lr = l & 15, lk = (l >> 4) * 8, g4 = (l >> 4) * 4;
  const int ct0 = wv * 2;

  // ---- phase 1: stage Psum (coalesced 16B gathers), d + dst to LDS ----
  {
    const int r = tid >> 2, qt = tid & 3;
    int e = e0 + r;
    int ec = (e < E) ? e : (E - 1);
    int es = eperm[ec];
    int s = esrc[es], t = edst[es];
    if (qt == 0) {
      dstv[r] = (e < E) ? t : -1;
      dval[r] = dbuf[es];
    }
    const half8t* ps = (const half8t*)(Ph + (size_t)s * 256);        // src proj
    const half8t* pt = (const half8t*)(Ph + (size_t)t * 256 + 128);  // dst proj
    half8t* pr = (half8t*)&SH[r * ES];
    #pragma unroll
    for (int i = 0; i < 4; ++i)
      pr[qt * 4 + i] = ps[qt * 4 + i] + pt[qt * 4 + i];   // v_pk_add_f16
  }
  __syncthreads();

  // ---- phase 2: acc init via identity-MFMA + K=16 rbf MFMA ----
  // aI[cj](l,i) = 1 iff (lk+i == cj*16+lr): D[m][n] = Psum[et*16+n][wv*32+cj*16+m]
  f32x4 acc[2][4];
  {
    half8t aI[2];
    #pragma unroll
    for (int cj = 0; cj < 2; ++cj)
      #pragma unroll
      for (int i = 0; i < 8; ++i)
        aI[cj][i] = (_Float16)((lk + i == cj * 16 + lr) ? 1.0f : 0.0f);
    const f32x4 z = {0.f, 0.f, 0.f, 0.f};
    #pragma unroll
    for (int et = 0; et < 4; ++et) {
      half8t bP = *(const half8t*)&SH[(et * 16 + lr) * ES + wv * 32 + lk];
      #pragma unroll
      for (int cj = 0; cj < 2; ++cj)
        acc[cj][et] = __builtin_amdgcn_mfma_f32_16x16x32_f16(aI[cj], bP, z, 0, 0, 0);
    }
  }
  {
    half4t br[4];
    #pragma unroll
    for (int et = 0; et < 4; ++et) {
      float d = dval[et * 16 + lr];
      #pragma unroll
      for (int i = 0; i < 4; ++i) {
        float dd = d - (float)(g4 + i) * (5.0f / 15.0f);
        br[et][i] = (_Float16)__expf(-10.24f * dd * dd);
      }
    }
    half4t ar[2];
    #pragma unroll
    for (int cj = 0; cj < 2; ++cj)
      ar[cj] = *(const half4t*)&Wr16[(((size_t)(ct0 + cj)) * 64 + l) * 4];
    #pragma unroll
    for (int et = 0; et < 4; ++et)
      #pragma unroll
      for (int cj = 0; cj < 2; ++cj)
        acc[cj][et] = __builtin_amdgcn_mfma_f32_16x16x16f16(ar[cj], br[et], acc[cj][et], 0, 0, 0);
  }
  __syncthreads();   // all Psum reads done -> buffer reusable for M1

  // ---- phase 3: silu -> M1 (aliases Psum region) ----
  #pragma unroll
  for (int cj = 0; cj < 2; ++cj) {
    f32x4 b1v = *(const f32x4*)&be1[(ct0 + cj) * 16 + g4];
    #pragma unroll
    for (int et = 0; et < 4; ++et) {
      half4t m4;
      #pragma unroll
      for (int rr = 0; rr < 4; ++rr)
        m4[rr] = (_Float16)silu_f(acc[cj][et][rr] + b1v[rr]);
      *(half4t*)&SH[(et * 16 + lr) * ES + (ct0 + cj) * 16 + g4] = m4;
    }
  }
  __syncthreads();

  // ---- phase 4: mm2T: acc2 = We2^T @ M1^T ----
  f32x4 acc2[2][4] = {};
  #pragma unroll
  for (int kt = 0; kt < 4; ++kt) {
    half8t a2[2], b2[4];
    #pragma unroll
    for (int cj = 0; cj < 2; ++cj)
      a2[cj] = *(const half8t*)&W2p[(((size_t)kt * 8 + ct0 + cj) * 64 + l) * 8];
    #pragma unroll
    for (int et = 0; et < 4; ++et)
      b2[et] = *(const half8t*)&SH[(et * 16 + lr) * ES + kt * 32 + lk];
    #pragma unroll
    for (int cj = 0; cj < 2; ++cj)
      #pragma unroll
      for (int et = 0; et < 4; ++et)
        acc2[cj][et] = __builtin_amdgcn_mfma_f32_16x16x32_f16(a2[cj], b2[et], acc2[cj][et], 0, 0, 0);
  }
  __syncthreads();   // M1 reads done -> buffer reusable for M2h

  // ---- phase 5: silu -> M2h (fp16, aliases again) ----
  #pragma unroll
  for (int cj = 0; cj < 2; ++cj) {
    f32x4 b2v = *(const f32x4*)&be2[(ct0 + cj) * 16 + g4];
    #pragma unroll
    for (int et = 0; et < 4; ++et) {
      half4t m4;
      #pragma unroll
      for (int rr = 0; rr < 4; ++rr)
        m4[rr] = (_Float16)silu_f(acc2[cj][et][rr] + b2v[rr]);
      *(half4t*)&SH[(et * 16 + lr) * ES + (ct0 + cj) * 16 + g4] = m4;
    }
  }
  __syncthreads();

  // ---- phase 6: segmented reduce over dst runs ----
  {
    int cp = tid & 63, qr = tid >> 6;
    int rbeg = qr * 16, rend = rbeg + 16;
    float a0 = 0.f, a1 = 0.f;
    int prev = -1;
    for (int r = rbeg; r < rend; ++r) {
      int dv = dstv[r];
      half2t v = *(const half2t*)&SH[r * ES + cp * 2];
      if (dv != prev) {
        if (prev >= 0) {
          atomicAdd(&agg[(size_t)prev * H + cp * 2], a0);
          atomicAdd(&agg[(size_t)prev * H + cp * 2 + 1], a1);
        }
        a0 = a1 = 0.f;
        prev = dv;
      }
      if (dv >= 0) { a0 += (float)v[0]; a1 += (float)v[1]; }
    }
    if (prev >= 0) {
      atomicAdd(&agg[(size_t)prev * H + cp * 2], a0);
      atomicAdd(&agg[(size_t)prev * H + cp * 2 + 1], a1);
    }
  }
}

// ---------------- fused node MLP + next-layer proj, 64 atoms/block ---------
// fp16 hb is the master h; residual read/write in fp16.
#define NXS2 264  // X stride fp16 (528B): [hb | agg]
#define US2 136

__global__ __launch_bounds__(256) void k_node_proj(
    unsigned short* __restrict__ hb,
    float* __restrict__ agg, int zero_agg,
    const unsigned short* __restrict__ W1p, const float* __restrict__ bh1,
    const unsigned short* __restrict__ W2p, const float* __restrict__ bh2,
    const unsigned short* __restrict__ Wp, const float* __restrict__ pbias,
    unsigned short* __restrict__ PhOut, int A) {
  __shared__ __align__(16) unsigned short X2[64 * NXS2];  // 33792 B
  __shared__ __align__(16) unsigned short Us2[64 * US2];  // 17408 B
  const int tid = threadIdx.x;
  const int a0 = blockIdx.x * 64;
  // ---- stage: 4 threads/row, 32 cols each; X=[hb | f16(agg)]; zero agg ----
  {
    const int r = tid >> 2, qt = tid & 3;
    int a = a0 + r; if (a >= A) a = A - 1;
    const u16x8* hr = (const u16x8*)(hb + (size_t)a * H + qt * 32);
    u16x8* xr = (u16x8*)&X2[r * NXS2 + qt * 32];
    xr[0] = hr[0]; xr[1] = hr[1]; xr[2] = hr[2]; xr[3] = hr[3];   // 32 elems
    float4* ar = (float4*)(agg + (size_t)a * H + qt * 32);
    u16x8 tmp[4];                              // 32 fp16
    unsigned short* tp = (unsigned short*)tmp;
    #pragma unroll
    for (int i = 0; i < 8; ++i) {              // 8 float4 = 32 floats
      float4 av = ar[i];
      tp[i*4+0] = f16u(av.x); tp[i*4+1] = f16u(av.y);
      tp[i*4+2] = f16u(av.z); tp[i*4+3] = f16u(av.w);
    }
    u16x8* xg = (u16x8*)&X2[r * NXS2 + 128 + qt * 32];
    xg[0] = tmp[0]; xg[1] = tmp[1]; xg[2] = tmp[2]; xg[3] = tmp[3];
    if (zero_agg) {
      float4 z = {0.f, 0.f, 0.f, 0.f};
      #pragma unroll
      for (int i = 0; i < 8; ++i) ar[i] = z;
    }
  }
  __syncthreads();

  const int l = tid & 63, wv = tid >> 6;
  const int lr = l & 15, lk = (l >> 4) * 8;
  const int ct0 = wv * 2;

  // ---- node mm1: [hb|agg](64x256) @ Wh1 -> U ----
  f32x4 acc[4][2] = {};
  #pragma unroll
  for (int kt = 0; kt < 8; ++kt) {
    half8t a[4], b[2];
    #pragma unroll
    for (int rt = 0; rt < 4; ++rt)
      a[rt] = *(const half8t*)&X2[(rt * 16 + lr) * NXS2 + kt * 32 + lk];
    #pragma unroll
    for (int j = 0; j < 2; ++j)
      b[j] = *(const half8t*)&W1p[(((size_t)kt * 8 + ct0 + j) * 64 + l) * 8];
    #pragma unroll
    for (int rt = 0; rt < 4; ++rt)
      #pragma unroll
      for (int j = 0; j < 2; ++j)
        acc[rt][j] = __builtin_amdgcn_mfma_f32_16x16x32_f16(a[rt], b[j], acc[rt][j], 0, 0, 0);
  }
  #pragma unroll
  for (int rt = 0; rt < 4; ++rt)
    #pragma unroll
    for (int j = 0; j < 2; ++j) {
      int col = (ct0 + j) * 16 + lr;
      float bb = bh1[col];
      #pragma unroll
      for (int rr = 0; rr < 4; ++rr) {
        int row = rt * 16 + (l >> 4) * 4 + rr;
        Us2[row * US2 + col] = f16u(silu_f(acc[rt][j][rr] + bb));
      }
    }
  __syncthreads();

  // ---- node mm2: U @ Wh2; residual update (fp16 master); newHb -> LDS ----
  f32x4 acc2[4][2] = {};
  #pragma unroll
  for (int kt = 0; kt < 4; ++kt) {
    half8t a[4], b[2];
    #pragma unroll
    for (int rt = 0; rt < 4; ++rt)
      a[rt] = *(const half8t*)&Us2[(rt * 16 + lr) * US2 + kt * 32 + lk];
    #pragma unroll
    for (int j = 0; j < 2; ++j)
      b[j] = *(const half8t*)&W2p[(((size_t)kt * 8 + ct0 + j) * 64 + l) * 8];
    #pragma unroll
    for (int rt = 0; rt < 4; ++rt)
      #pragma unroll
      for (int j = 0; j < 2; ++j)
        acc2[rt][j] = __builtin_amdgcn_mfma_f32_16x16x32_f16(a[rt], b[j], acc2[rt][j], 0, 0, 0);
  }
  unsigned short* NH = X2;   // X2 dead after mm1 reads
  __syncthreads();
  #pragma unroll
  for (int rt = 0; rt < 4; ++rt)
    #pragma unroll
    for (int j = 0; j < 2; ++j) {
      int col = (ct0 + j) * 16 + lr;
      float bb = bh2[col];
      #pragma unroll
      for (int rr = 0; rr < 4; ++rr) {
        int row = rt * 16 + (l >> 4) * 4 + rr;
        int a = a0 + row;
        float nh = 0.0f;
        if (a < A) {
          size_t off = (size_t)a * H + col;
          float oldh = (float)(*(const _Float16*)&hb[off]);   // L2-hot
          nh = oldh + acc2[rt][j][rr] + bb;
          hb[off] = f16u(nh);
        }
        NH[row * US2 + col] = f16u(nh);
      }
    }
  __syncthreads();

  // ---- proj: PhOut = newHb @ Wp (+pbias) ----
  f32x4 accp[4][4] = {};
  #pragma unroll
  for (int kt = 0; kt < 4; ++kt) {
    half8t a[4], b[4];
    #pragma unroll
    for (int rt = 0; rt < 4; ++rt)
      a[rt] = *(const half8t*)&NH[(rt * 16 + lr) * US2 + kt * 32 + lk];
    #pragma unroll
    for (int ci = 0; ci < 4; ++ci)
      b[ci] = *(const half8t*)&Wp[(((size_t)kt * 16 + wv * 4 + ci) * 64 + l) * 8];
    #pragma unroll
    for (int rt = 0; rt < 4; ++rt)
      #pragma unroll
      for (int ci = 0; ci < 4; ++ci)
        accp[rt][ci] = __builtin_amdgcn_mfma_f32_16x16x32_f16(a[rt], b[ci], accp[rt][ci], 0, 0, 0);
  }
  #pragma unroll
  for (int rt = 0; rt < 4; ++rt)
    #pragma unroll
    for (int ci = 0; ci < 4; ++ci) {
      int col = (wv * 4 + ci) * 16 + lr;
      float bb = pbias ? pbias[col] : 0.0f;
      #pragma unroll
      for (int rr = 0; rr < 4; ++rr) {
        int row = a0 + rt * 16 + (l >> 4) * 4 + rr;
        if (row < A) PhOut[(size_t)row * 256 + col] = f16u(accp[rt][ci][rr] + bb);
      }
    }
}

// ---------------- tail kernels ---------------------------------------------
__global__ void k_q4b(const float* __restrict__ residue_embed,
                      const float* __restrict__ Wq, const float* __restrict__ bq,
                      const float* __restrict__ bk, const float* __restrict__ bv,
                      float* __restrict__ q4, float* __restrict__ bkv) {
  int i = blockIdx.x * blockDim.x + threadIdx.x;
  if (i < 512) {
    int r = i >> 7, j = i & 127;
    const float* emb = residue_embed + (size_t)r * H;
    float s = bq[j];
    #pragma unroll 4
    for (int k = 0; k < H; ++k) s += emb[k] * Wq[(size_t)k*H + j];
    q4[i] = s;
  } else if (i < 768) {
    int t = i - 512;
    bkv[t] = (t < 128) ? bk[t] : bv[t - 128];
  }
}

// scores[a] = (k[a] . q4[rtype[ridx[a]]]) * H^-0.5   (4 lanes per atom)
__global__ void k_score(const unsigned short* __restrict__ kv,
                        const float* __restrict__ q4,
                        const int* __restrict__ ridx,
                        const int* __restrict__ rtype,
                        float* __restrict__ scores, int A) {
  int t = blockIdx.x * blockDim.x + threadIdx.x;
  int a = t >> 2, qt = t & 3;
  if (a >= A) return;
  const half8t* kr = (const half8t*)(kv + (size_t)a * 256 + qt * 32);
  const float* qrow = q4 + (size_t)rtype[ridx[a]] * H + qt * 32;
  float s = 0.f;
  #pragma unroll
  for (int i = 0; i < 4; ++i) {
    half8t kvv = kr[i];
    #pragma unroll
    for (int j = 0; j < 8; ++j) s += (float)kvv[j] * qrow[i * 8 + j];
  }
  s += __shfl_xor(s, 1);
  s += __shfl_xor(s, 2);
  if (qt == 0) scores[a] = s * 0.08838834764831845f;
}

// per-residue softmax + PV over fp16 kv rows [k(128) | v(128)]
__global__ __launch_bounds__(256) void k_pool(
    const float* __restrict__ scores,
    const unsigned short* __restrict__ kv, const int* __restrict__ starts,
    const int* __restrict__ apr, float* __restrict__ pooled, int N) {
  int r = blockIdx.x * 4 + (threadIdx.x >> 6);
  if (r >= N) return;
  int lane = threadIdx.x & 63;
  int s0 = starts[r], cnt = apr[r];
  float val = (lane < cnt) ? scores[s0 + lane] : -1e30f;
  float mx = val;
  #pragma unroll
  for (int off = 32; off; off >>= 1) mx = fmaxf(mx, __shfl_xor(mx, off));
  float ex = (lane < cnt) ? __expf(val - mx) : 0.0f;
  float sum = ex;
  #pragma unroll
  for (int off = 32; off; off >>= 1) sum += __shfl_xor(sum, off);
  float w = ex * __builtin_amdgcn_rcpf(sum);
  float p0 = 0.f, p1 = 0.f;
  for (int i = 0; i < cnt; ++i) {
    float wi = __shfl(w, i);
    const unsigned short* vr = kv + (size_t)(s0 + i) * 256 + 128;
    p0 += wi * (float)(*(const _Float16*)&vr[lane]);
    p1 += wi * (float)(*(const _Float16*)&vr[64 + lane]);
  }
  pooled[(size_t)r*H + lane] = p0;
  pooled[(size_t)r*H + 64 + lane] = p1;
}

__global__ void k_head(const float* __restrict__ pooled,
                       const float* __restrict__ Wmu, const float* __restrict__ bmu,
                       const float* __restrict__ Wlv, const float* __restrict__ blv,
                       float* __restrict__ out, int N) {
  int i = blockIdx.x * blockDim.x + threadIdx.x;
  if (i >= N * LATD) return;
  int r = i >> 5, j = i & 31;
  const float* p = pooled + (size_t)r * H;
  float smu = 0.f, slv = 0.f;
  #pragma unroll 4
  for (int k = 0; k < H; ++k) {
    float pv = p[k];
    smu += pv * Wmu[(size_t)k*LATD + j];
    slv += pv * Wlv[(size_t)k*LATD + j];
  }
  smu += bmu[j];
  slv += blv[j];
  slv = fminf(fmaxf(slv, -10.0f), 2.0f);
  out[i] = smu;
  out[(size_t)N*LATD + i] = slv;
}

extern "C" void kernel_launch(void* const* d_in, const int* in_sizes, int n_in,
                              void* d_out, int out_size, void* d_ws, size_t ws_size,
                              hipStream_t stream) {
  const float* coords        = (const float*)d_in[0];
  const int*   atype         = (const int*)d_in[1];
  const int*   ridx          = (const int*)d_in[2];
  const int*   rtype         = (const int*)d_in[3];
  const int*   apr           = (const int*)d_in[4];
  const int*   esrc          = (const int*)d_in[5];
  const int*   edst          = (const int*)d_in[6];
  const float* atom_embed    = (const float*)d_in[7];
  const float* residue_embed = (const float*)d_in[8];
  const float* We1 = (const float*)d_in[9];
  const float* be1 = (const float*)d_in[10];
  const float* We2 = (const float*)d_in[11];
  const float* be2 = (const float*)d_in[12];
  const float* Wh1 = (const float*)d_in[13];
  const float* bh1 = (const float*)d_in[14];
  const float* Wh2 = (const float*)d_in[15];
  const float* bh2 = (const float*)d_in[16];
  const float* Wq  = (const float*)d_in[17];
  const float* bq  = (const float*)d_in[18];
  const float* Wk  = (const float*)d_in[19];
  const float* bk  = (const float*)d_in[20];
  const float* Wv  = (const float*)d_in[21];
  const float* bv  = (const float*)d_in[22];
  const float* Wmu = (const float*)d_in[23];
  const float* bmu = (const float*)d_in[24];
  const float* Wlv = (const float*)d_in[25];
  const float* blv = (const float*)d_in[26];

  const int A = in_sizes[1];
  const int N = in_sizes[3];
  const int E = in_sizes[5];

  float4* c4    = (float4*)d_ws;                   // A float4 (16B-aligned base)
  float* agg    = (float*)(c4 + A);                // A*H f32
  float* vbuf   = agg + (size_t)A * H;             // A*H f32 (aliased: Ph, then kv)
  float* dbuf   = vbuf + (size_t)A * H;            // E f32 (later: scores, A<=E)
  float* q4     = dbuf + (size_t)E;                // 4*H
  float* bkv    = q4 + 4 * H;                      // 256
  float* pooled = bkv + 256;                       // N*H
  int*   starts = (int*)(pooled + (size_t)N * H);  // N
  unsigned short* hbuf = (unsigned short*)(starts + N);  // A*H fp16 (master h)
  int*   eperm  = (int*)(hbuf + (size_t)A * H);    // E
  int*   cnt    = eperm + (size_t)E;               // A
  int*   cursor = cnt + A;                         // A
  int*   bsum   = cursor + A;                      // 64
  unsigned short* wp = (unsigned short*)(bsum + 64);     // WP_TOTAL fp16
  unsigned short* Ph = (unsigned short*)vbuf;      // A*256 fp16 == A*H f32 bytes

  hipMemsetAsync(cnt, 0, (size_t)A * sizeof(int), stream);
  k_pack<<<(WP_TOTAL + 255) / 256, 256, 0, stream>>>(We1, We2, Wh1, Wh2, Wk, Wv, wp);
  k_q4b<<<3, 256, 0, stream>>>(residue_embed, Wq, bq, bk, bv, q4, bkv);
  k_pad4<<<(A + 255) / 256, 256, 0, stream>>>(coords, c4, A);
  k_dist<<<(E + 255) / 256, 256, 0, stream>>>(c4, esrc, edst, dbuf, cnt, E);
  // fused: embed-init + starts + agg-zero + layer-0 proj
  k_init_proj<<<(A + 63) / 64, 256, 0, stream>>>(
      atom_embed, residue_embed, atype, ridx, rtype,
      hbuf, starts, agg, wp + OFF_PROJ, Ph, A);

  // counting sort of edges by dst (two-level scan; scanC fused into scatter)
  const int nb = (A + 1023) / 1024;
  k_scanA<<<nb, 1024, 0, stream>>>(cnt, cursor, bsum, A);
  k_scanB<<<1, 64, 0, stream>>>(bsum, nb);
  k_scatter<<<(E + 255) / 256, 256, 0, stream>>>(edst, cursor, bsum, eperm, E);

  const int egrid = (E + 63) / 64;
  unsigned short* kv = Ph;  // layer-2 node_proj writes kv into the same region
  for (int l = 0; l < 3; ++l) {
    k_edge_mfma<<<egrid, 256, 0, stream>>>(
        Ph, dbuf, esrc, edst, eperm,
        wp + OFF_RBF16 + (size_t)l * 2048, be1 + (size_t)l * H,
        wp + OFF_W2    + (size_t)l * 16384, be2 + (size_t)l * H, agg, E);
    const unsigned short* Wnext =
        (l < 2) ? (wp + OFF_PROJ + (size_t)(l + 1) * 32768) : (wp + OFF_KV);
    k_node_proj<<<(A + 63) / 64, 256, 0, stream>>>(
        hbuf, agg, (l < 2) ? 1 : 0,
        wp + OFF_H1 + (size_t)l * 32768, bh1 + (size_t)l * H,
        wp + OFF_H2 + (size_t)l * 16384, bh2 + (size_t)l * H,
        Wnext, (l < 2) ? nullptr : bkv, Ph, A);
  }

  float* scores = dbuf;     // dbuf dead after last edge; A <= E
  k_score<<<(A * 4 + 255) / 256, 256, 0, stream>>>(kv, q4, ridx, rtype, scores, A);
  k_pool<<<(N + 3) / 4, 256, 0, stream>>>(scores, kv, starts, apr, pooled, N);
  k_head<<<(N * LATD + 255) / 256, 256, 0, stream>>>(pooled, Wmu, bmu, Wlv, blv,
                                                     (float*)d_out, N);
}

// Round 15
// 584.054 us; speedup vs baseline: 1.0900x; 1.0900x over previous
//
#include <hip/hip_runtime.h>
#include <hip/hip_bf16.h>

#define H 128
#define LATD 32

typedef __attribute__((ext_vector_type(8))) _Float16 half8t;        // 8 fp16
typedef __attribute__((ext_vector_type(4))) _Float16 half4t;        // 4 fp16
typedef __attribute__((ext_vector_type(2))) _Float16 half2t;        // 2 fp16
typedef __attribute__((ext_vector_type(8))) unsigned short u16x8;   // 16B copy unit
typedef __attribute__((ext_vector_type(4))) float f32x4;

// packed-weight region offsets (u16 elements)
#define OFF_W2  12288     // 3 x [4kt][8ct][64][8]   (We2)
#define OFF_PROJ 61440    // 3 x [4kt][16ct][64][8]  ([We1_src | We1_dst] 128x256)
#define OFF_H1  159744    // 3 x [8kt][8ct][64][8]   (Wh1)
#define OFF_H2  258048    // 3 x [4kt][8ct][64][8]   (Wh2)
#define OFF_KV  307200    // 1 x [4kt][16ct][64][8]  ([Wk | Wv] 128x256)
#define OFF_RBF16 339968  // 3 x [8ct][64][4]        (We1 rows 256..271, K=16 frags)
#define WP_TOTAL 346112

// silu via native rcp (avoids IEEE div sequence)
__device__ __forceinline__ float silu_f(float x) {
  return x * __builtin_amdgcn_rcpf(1.0f + __expf(-x));
}
__device__ __forceinline__ unsigned short f16u(float x) {
  _Float16 hh = (_Float16)x;
  return *(unsigned short*)&hh;
}

// fused: distance + dst histogram (cnt must be zeroed before launch)
__global__ void k_dist(const float* __restrict__ coords,
                       const int* __restrict__ esrc, const int* __restrict__ edst,
                       float* __restrict__ dbuf, int* __restrict__ cnt, int E) {
  int e = blockIdx.x * blockDim.x + threadIdx.x;
  if (e >= E) return;
  int s = esrc[e], t = edst[e];
  float dx = coords[3*s+0] - coords[3*t+0];
  float dy = coords[3*s+1] - coords[3*t+1];
  float dz = coords[3*s+2] - coords[3*t+2];
  dbuf[e] = sqrtf(dx*dx + dy*dy + dz*dz);
  atomicAdd(&cnt[t], 1);
}

__global__ __launch_bounds__(1024) void k_scanA(const int* __restrict__ cnt,
                                                int* __restrict__ cursor,
                                                int* __restrict__ bsum, int A) {
  __shared__ int buf[1024];
  int tid = threadIdx.x;
  int i = blockIdx.x * 1024 + tid;
  int v = (i < A) ? cnt[i] : 0;
  buf[tid] = v;
  __syncthreads();
  #pragma unroll
  for (int off = 1; off < 1024; off <<= 1) {
    int nv = (tid >= off) ? buf[tid - off] : 0;
    __syncthreads();
    buf[tid] += nv;
    __syncthreads();
  }
  if (i < A) cursor[i] = buf[tid] - v;   // exclusive within chunk
  if (tid == 1023) bsum[blockIdx.x] = buf[1023];
}

__global__ void k_scanB(int* __restrict__ bsum, int nb) {
  int lane = threadIdx.x;                 // one wave, nb <= 64
  int v = (lane < nb) ? bsum[lane] : 0;
  int s = v;
  #pragma unroll
  for (int off = 1; off < 64; off <<= 1) {
    int nv = __shfl_up(s, off);
    if (lane >= off) s += nv;
  }
  if (lane < nb) bsum[lane] = s - v;      // exclusive
}

// scatter with fused scanC: final position = local-scan + chunk offset
__global__ void k_scatter(const int* __restrict__ edst, int* __restrict__ cursor,
                          const int* __restrict__ bsum,
                          int* __restrict__ eperm, int E) {
  int e = blockIdx.x * blockDim.x + threadIdx.x;
  if (e >= E) return;
  int t = edst[e];
  int p = atomicAdd(&cursor[t], 1) + bsum[t >> 10];
  eperm[p] = e;
}

// ---------------- weight packing into per-lane-contiguous fragments --------
__global__ void k_pack(const float* __restrict__ We1, const float* __restrict__ We2,
                       const float* __restrict__ Wh1, const float* __restrict__ Wh2,
                       const float* __restrict__ Wk,  const float* __restrict__ Wv,
                       unsigned short* __restrict__ wp) {
  int t = blockIdx.x * blockDim.x + threadIdx.x;
  if (t >= WP_TOTAL) return;
  if (t < OFF_W2) {                      // legacy region (unused)
    wp[t] = 0;
  } else if (t < OFF_PROJ) {             // We2 128x128
    int u = t - OFF_W2; int layer = u / 16384, idx = u % 16384;
    int i = idx & 7, lane = (idx >> 3) & 63, ct = (idx >> 9) & 7, kt = idx >> 12;
    int k = kt * 32 + (lane >> 4) * 8 + i, c = ct * 16 + (lane & 15);
    const float* src = We2 + (size_t)layer * 128 * H;
    wp[t] = f16u(src[(size_t)k * H + c]);
  } else if (t < OFF_H1) {               // proj: [We1_src | We1_dst] 128x256
    int u = t - OFF_PROJ; int layer = u / 32768, idx = u % 32768;
    int i = idx & 7, lane = (idx >> 3) & 63, ct = (idx >> 9) & 15, kt = idx >> 13;
    int k = kt * 32 + (lane >> 4) * 8 + i, c = ct * 16 + (lane & 15);
    const float* src = We1 + (size_t)layer * 272 * H;
    float v = (c < 128) ? src[(size_t)k * H + c] : src[(size_t)(128 + k) * H + (c - 128)];
    wp[t] = f16u(v);
  } else if (t < OFF_H2) {               // Wh1 256x128
    int u = t - OFF_H1; int layer = u / 32768, idx = u % 32768;
    int i = idx & 7, lane = (idx >> 3) & 63, ct = (idx >> 9) & 7, kt = idx >> 12;
    int k = kt * 32 + (lane >> 4) * 8 + i, c = ct * 16 + (lane & 15);
    const float* src = Wh1 + (size_t)layer * 256 * H;
    wp[t] = f16u(src[(size_t)k * H + c]);
  } else if (t < OFF_KV) {               // Wh2 128x128
    int u = t - OFF_H2; int layer = u / 16384, idx = u % 16384;
    int i = idx & 7, lane = (idx >> 3) & 63, ct = (idx >> 9) & 7, kt = idx >> 12;
    int k = kt * 32 + (lane >> 4) * 8 + i, c = ct * 16 + (lane & 15);
    const float* src = Wh2 + (size_t)layer * 128 * H;
    wp[t] = f16u(src[(size_t)k * H + c]);
  } else if (t < OFF_RBF16) {            // [Wk | Wv] 128x256
    int idx = t - OFF_KV;
    int i = idx & 7, lane = (idx >> 3) & 63, ct = (idx >> 9) & 15, kt = idx >> 13;
    int k = kt * 32 + (lane >> 4) * 8 + i, c = ct * 16 + (lane & 15);
    float v = (c < 128) ? Wk[(size_t)k * H + c] : Wv[(size_t)k * H + (c - 128)];
    wp[t] = f16u(v);
  } else {                               // rbf16: We1 rows 256..271 as K=16 A-frags
    int u = t - OFF_RBF16; int layer = u / 2048, idx = u % 2048;
    int i = idx & 3, lane = (idx >> 2) & 63, ct = idx >> 8;
    int k = (lane >> 4) * 4 + i;
    int c = ct * 16 + (lane & 15);
    const float* src = We1 + (size_t)layer * 272 * H;
    wp[t] = f16u(src[(size_t)(256 + k) * H + c]);
  }
}

// ---------------- fused init: embed-init + starts + agg-zero + proj(l0) ----
#define PS2 136   // LDS hb stride (fp16)

__global__ __launch_bounds__(256) void k_init_proj(
    const float* __restrict__ atom_embed, const float* __restrict__ residue_embed,
    const int* __restrict__ atype, const int* __restrict__ ridx,
    const int* __restrict__ rtype,
    float* __restrict__ h, unsigned short* __restrict__ hb,
    int* __restrict__ starts, float* __restrict__ agg,
    const unsigned short* __restrict__ Wp, unsigned short* __restrict__ Ph, int A) {
  __shared__ __align__(16) unsigned short Xp[64 * PS2];   // 17408 B
  const int tid = threadIdx.x;
  const int a0 = blockIdx.x * 64;
  {
    const int r = tid >> 2, qt = tid & 3;
    int a = a0 + r;
    int ac = (a < A) ? a : (A - 1);
    int ri = ridx[ac];
    const float* ae = atom_embed + (size_t)atype[ac] * H + qt * 32;
    const float* re = residue_embed + (size_t)rtype[ri] * H + qt * 32;
    if (a < A) {
      if (qt == 0 && (a == 0 || ridx[a - 1] != ri)) starts[ri] = a;
      float4 z = {0.f, 0.f, 0.f, 0.f};
      float4* az = (float4*)(agg + (size_t)a * H + qt * 32);
      #pragma unroll
      for (int i = 0; i < 8; ++i) az[i] = z;
      #pragma unroll
      for (int j = 0; j < 32; ++j) {
        float v = ae[j] + re[j];
        h[(size_t)a * H + qt * 32 + j] = v;
        unsigned short u = f16u(v);
        hb[(size_t)a * H + qt * 32 + j] = u;
        Xp[r * PS2 + qt * 32 + j] = u;
      }
    } else {
      #pragma unroll
      for (int j = 0; j < 32; ++j) {
        float v = ae[j] + re[j];
        Xp[r * PS2 + qt * 32 + j] = f16u(v);
      }
    }
  }
  __syncthreads();
  const int l = tid & 63, wv = tid >> 6;
  const int lr = l & 15, lk = (l >> 4) * 8;
  f32x4 acc[4][4] = {};
  #pragma unroll
  for (int kt = 0; kt < 4; ++kt) {
    half8t a[4], b[4];
    #pragma unroll
    for (int rt = 0; rt < 4; ++rt)
      a[rt] = *(const half8t*)&Xp[(rt * 16 + lr) * PS2 + kt * 32 + lk];
    #pragma unroll
    for (int ci = 0; ci < 4; ++ci)
      b[ci] = *(const half8t*)&Wp[(((size_t)kt * 16 + wv * 4 + ci) * 64 + l) * 8];
    #pragma unroll
    for (int rt = 0; rt < 4; ++rt)
      #pragma unroll
      for (int ci = 0; ci < 4; ++ci)
        acc[rt][ci] = __builtin_amdgcn_mfma_f32_16x16x32_f16(a[rt], b[ci], acc[rt][ci], 0, 0, 0);
  }
  #pragma unroll
  for (int rt = 0; rt < 4; ++rt)
    #pragma unroll
    for (int ci = 0; ci < 4; ++ci) {
      int col = (wv * 4 + ci) * 16 + lr;
      #pragma unroll
      for (int rr = 0; rr < 4; ++rr) {
        int row = a0 + rt * 16 + (l >> 4) * 4 + rr;
        if (row < A) Ph[(size_t)row * 256 + col] = f16u(acc[rt][ci][rr]);
      }
    }
}

// ---------------- edge kernel (r13-proven config + XCD swizzle) ------------
#define ES 136    // shared stride (fp16): 272B/row, 16B-aligned
#define NXCD 8

__global__ __launch_bounds__(256) void k_edge_mfma(
    const unsigned short* __restrict__ Ph, const float* __restrict__ dbuf,
    const int* __restrict__ esrc, const int* __restrict__ edst,
    const int* __restrict__ eperm,
    const unsigned short* __restrict__ Wr16, const float* __restrict__ be1,
    const unsigned short* __restrict__ W2p, const float* __restrict__ be2,
    float* __restrict__ agg, int E) {
  __shared__ __align__(16) unsigned short SH[64 * ES];  // 17408 B (Psum/M1/M2h)
  __shared__ int dstv[64];
  __shared__ float dval[64];

  const int tid = threadIdx.x;
  // bijective XCD-aware swizzle (m204): each XCD gets a contiguous chunk of
  // dst-sorted edge blocks -> L2-local Ph gathers + agg atomics.
  int bid = blockIdx.x, nwg = gridDim.x;
  int qq = nwg / NXCD, rr8 = nwg % NXCD;
  int xcd = bid % NXCD, idx = bid / NXCD;
  int swz = (xcd < rr8 ? xcd * (qq + 1) : rr8 * (qq + 1) + (xcd - rr8) * qq) + idx;
  const int e0 = swz * 64;
  const int l = tid & 63, wv = tid >> 6;
  const int lr = l & 15, lk = (l >> 4) * 8, g4 = (l >> 4) * 4;
  const int ct0 = wv * 2;

  // ---- phase 1: stage Psum (coalesced 16B gathers), d + dst to LDS ----
  {
    const int r = tid >> 2, qt = tid & 3;
    int e = e0 + r;
    int ec = (e < E) ? e : (E - 1);
    int es = eperm[ec];
    int s = esrc[es], t = edst[es];
    if (qt == 0) {
      dstv[r] = (e < E) ? t : -1;
      dval[r] = dbuf[es];
    }
    const half8t* ps = (const half8t*)(Ph + (size_t)s * 256);        // src proj
    const half8t* pt = (const half8t*)(Ph + (size_t)t * 256 + 128);  // dst proj
    half8t* pr = (half8t*)&SH[r * ES];
    #pragma unroll
    for (int i = 0; i < 4; ++i)
      pr[qt * 4 + i] = ps[qt * 4 + i] + pt[qt * 4 + i];   // v_pk_add_f16
  }
  __syncthreads();

  // ---- phase 2: acc init from Psum slivers + K=16 rbf MFMA ----
  f32x4 acc[2][4];
  #pragma unroll
  for (int cj = 0; cj < 2; ++cj) {
    int cbase = (ct0 + cj) * 16 + g4;
    #pragma unroll
    for (int et = 0; et < 4; ++et) {
      half4t p4 = *(const half4t*)&SH[(et * 16 + lr) * ES + cbase];
      acc[cj][et][0] = (float)p4[0];
      acc[cj][et][1] = (float)p4[1];
      acc[cj][et][2] = (float)p4[2];
      acc[cj][et][3] = (float)p4[3];
    }
  }
  {
    half4t br[4];
    #pragma unroll
    for (int et = 0; et < 4; ++et) {
      float d = dval[et * 16 + lr];
      #pragma unroll
      for (int i = 0; i < 4; ++i) {
        float dd = d - (float)(g4 + i) * (5.0f / 15.0f);
        br[et][i] = (_Float16)__expf(-10.24f * dd * dd);
      }
    }
    half4t ar[2];
    #pragma unroll
    for (int cj = 0; cj < 2; ++cj)
      ar[cj] = *(const half4t*)&Wr16[(((size_t)(ct0 + cj)) * 64 + l) * 4];
    #pragma unroll
    for (int et = 0; et < 4; ++et)
      #pragma unroll
      for (int cj = 0; cj < 2; ++cj)
        acc[cj][et] = __builtin_amdgcn_mfma_f32_16x16x16f16(ar[cj], br[et], acc[cj][et], 0, 0, 0);
  }
  __syncthreads();   // all Psum reads done -> buffer reusable for M1

  // ---- phase 3: silu -> M1 (aliases Psum region) ----
  #pragma unroll
  for (int cj = 0; cj < 2; ++cj) {
    f32x4 b1v = *(const f32x4*)&be1[(ct0 + cj) * 16 + g4];
    #pragma unroll
    for (int et = 0; et < 4; ++et) {
      half4t m4;
      #pragma unroll
      for (int rr = 0; rr < 4; ++rr)
        m4[rr] = (_Float16)silu_f(acc[cj][et][rr] + b1v[rr]);
      *(half4t*)&SH[(et * 16 + lr) * ES + (ct0 + cj) * 16 + g4] = m4;
    }
  }
  __syncthreads();

  // ---- phase 4: mm2T: acc2 = We2^T @ M1^T ----
  f32x4 acc2[2][4] = {};
  #pragma unroll
  for (int kt = 0; kt < 4; ++kt) {
    half8t a2[2], b2[4];
    #pragma unroll
    for (int cj = 0; cj < 2; ++cj)
      a2[cj] = *(const half8t*)&W2p[(((size_t)kt * 8 + ct0 + cj) * 64 + l) * 8];
    #pragma unroll
    for (int et = 0; et < 4; ++et)
      b2[et] = *(const half8t*)&SH[(et * 16 + lr) * ES + kt * 32 + lk];
    #pragma unroll
    for (int cj = 0; cj < 2; ++cj)
      #pragma unroll
      for (int et = 0; et < 4; ++et)
        acc2[cj][et] = __builtin_amdgcn_mfma_f32_16x16x32_f16(a2[cj], b2[et], acc2[cj][et], 0, 0, 0);
  }
  __syncthreads();   // M1 reads done -> buffer reusable for M2h

  // ---- phase 5: silu -> M2h (fp16, aliases again) ----
  #pragma unroll
  for (int cj = 0; cj < 2; ++cj) {
    f32x4 b2v = *(const f32x4*)&be2[(ct0 + cj) * 16 + g4];
    #pragma unroll
    for (int et = 0; et < 4; ++et) {
      half4t m4;
      #pragma unroll
      for (int rr = 0; rr < 4; ++rr)
        m4[rr] = (_Float16)silu_f(acc2[cj][et][rr] + b2v[rr]);
      *(half4t*)&SH[(et * 16 + lr) * ES + (ct0 + cj) * 16 + g4] = m4;
    }
  }
  __syncthreads();

  // ---- phase 6: segmented reduce over dst runs ----
  {
    int cp = tid & 63, qr = tid >> 6;
    int rbeg = qr * 16, rend = rbeg + 16;
    float a0 = 0.f, a1 = 0.f;
    int prev = -1;
    for (int r = rbeg; r < rend; ++r) {
      int dv = dstv[r];
      half2t v = *(const half2t*)&SH[r * ES + cp * 2];
      if (dv != prev) {
        if (prev >= 0) {
          atomicAdd(&agg[(size_t)prev * H + cp * 2], a0);
          atomicAdd(&agg[(size_t)prev * H + cp * 2 + 1], a1);
        }
        a0 = a1 = 0.f;
        prev = dv;
      }
      if (dv >= 0) { a0 += (float)v[0]; a1 += (float)v[1]; }
    }
    if (prev >= 0) {
      atomicAdd(&agg[(size_t)prev * H + cp * 2], a0);
      atomicAdd(&agg[(size_t)prev * H + cp * 2 + 1], a1);
    }
  }
}

// ---------------- fused node MLP + next-layer proj, 64 atoms/block ---------
#define NXS2 264  // X stride fp16 (528B): [hb | agg]
#define US2 136

__global__ __launch_bounds__(256) void k_node_proj(
    float* __restrict__ h, unsigned short* __restrict__ hb,
    float* __restrict__ agg, int zero_agg,
    const unsigned short* __restrict__ W1p, const float* __restrict__ bh1,
    const unsigned short* __restrict__ W2p, const float* __restrict__ bh2,
    const unsigned short* __restrict__ Wp, const float* __restrict__ pbias,
    unsigned short* __restrict__ PhOut, int A) {
  __shared__ __align__(16) unsigned short X2[64 * NXS2];  // 33792 B
  __shared__ __align__(16) unsigned short Us2[64 * US2];  // 17408 B
  const int tid = threadIdx.x;
  const int a0 = blockIdx.x * 64;
  // ---- stage: 4 threads/row, 32 cols each; X=[hb | f16(agg)]; zero agg ----
  {
    const int r = tid >> 2, qt = tid & 3;
    int a = a0 + r; if (a >= A) a = A - 1;
    const u16x8* hr = (const u16x8*)(hb + (size_t)a * H + qt * 32);
    u16x8* xr = (u16x8*)&X2[r * NXS2 + qt * 32];
    xr[0] = hr[0]; xr[1] = hr[1]; xr[2] = hr[2]; xr[3] = hr[3];   // 32 elems
    float4* ar = (float4*)(agg + (size_t)a * H + qt * 32);
    u16x8 tmp[4];                              // 32 fp16
    unsigned short* tp = (unsigned short*)tmp;
    #pragma unroll
    for (int i = 0; i < 8; ++i) {              // 8 float4 = 32 floats
      float4 av = ar[i];
      tp[i*4+0] = f16u(av.x); tp[i*4+1] = f16u(av.y);
      tp[i*4+2] = f16u(av.z); tp[i*4+3] = f16u(av.w);
    }
    u16x8* xg = (u16x8*)&X2[r * NXS2 + 128 + qt * 32];
    xg[0] = tmp[0]; xg[1] = tmp[1]; xg[2] = tmp[2]; xg[3] = tmp[3];
    if (zero_agg) {
      float4 z = {0.f, 0.f, 0.f, 0.f};
      #pragma unroll
      for (int i = 0; i < 8; ++i) ar[i] = z;
    }
  }
  __syncthreads();

  const int l = tid & 63, wv = tid >> 6;
  const int lr = l & 15, lk = (l >> 4) * 8;
  const int ct0 = wv * 2;

  // ---- node mm1: [hb|agg](64x256) @ Wh1 -> U ----
  f32x4 acc[4][2] = {};
  #pragma unroll
  for (int kt = 0; kt < 8; ++kt) {
    half8t a[4], b[2];
    #pragma unroll
    for (int rt = 0; rt < 4; ++rt)
      a[rt] = *(const half8t*)&X2[(rt * 16 + lr) * NXS2 + kt * 32 + lk];
    #pragma unroll
    for (int j = 0; j < 2; ++j)
      b[j] = *(const half8t*)&W1p[(((size_t)kt * 8 + ct0 + j) * 64 + l) * 8];
    #pragma unroll
    for (int rt = 0; rt < 4; ++rt)
      #pragma unroll
      for (int j = 0; j < 2; ++j)
        acc[rt][j] = __builtin_amdgcn_mfma_f32_16x16x32_f16(a[rt], b[j], acc[rt][j], 0, 0, 0);
  }
  #pragma unroll
  for (int rt = 0; rt < 4; ++rt)
    #pragma unroll
    for (int j = 0; j < 2; ++j) {
      int col = (ct0 + j) * 16 + lr;
      float bb = bh1[col];
      #pragma unroll
      for (int rr = 0; rr < 4; ++rr) {
        int row = rt * 16 + (l >> 4) * 4 + rr;
        Us2[row * US2 + col] = f16u(silu_f(acc[rt][j][rr] + bb));
      }
    }
  __syncthreads();

  // ---- node mm2: U @ Wh2; residual update; new hb -> LDS (aliases X2) ----
  f32x4 acc2[4][2] = {};
  #pragma unroll
  for (int kt = 0; kt < 4; ++kt) {
    half8t a[4], b[2];
    #pragma unroll
    for (int rt = 0; rt < 4; ++rt)
      a[rt] = *(const half8t*)&Us2[(rt * 16 + lr) * US2 + kt * 32 + lk];
    #pragma unroll
    for (int j = 0; j < 2; ++j)
      b[j] = *(const half8t*)&W2p[(((size_t)kt * 8 + ct0 + j) * 64 + l) * 8];
    #pragma unroll
    for (int rt = 0; rt < 4; ++rt)
      #pragma unroll
      for (int j = 0; j < 2; ++j)
        acc2[rt][j] = __builtin_amdgcn_mfma_f32_16x16x32_f16(a[rt], b[j], acc2[rt][j], 0, 0, 0);
  }
  unsigned short* NH = X2;   // X2 dead after mm1 reads
  __syncthreads();
  #pragma unroll
  for (int rt = 0; rt < 4; ++rt)
    #pragma unroll
    for (int j = 0; j < 2; ++j) {
      int col = (ct0 + j) * 16 + lr;
      float bb = bh2[col];
      #pragma unroll
      for (int rr = 0; rr < 4; ++rr) {
        int row = rt * 16 + (l >> 4) * 4 + rr;
        int a = a0 + row;
        float nh = 0.0f;
        if (a < A) {
          size_t off = (size_t)a * H + col;
          nh = h[off] + acc2[rt][j][rr] + bb;
          h[off] = nh;
          hb[off] = f16u(nh);
        }
        NH[row * US2 + col] = f16u(nh);
      }
    }
  __syncthreads();

  // ---- proj: PhOut = newHb @ Wp (+pbias) ----
  f32x4 accp[4][4] = {};
  #pragma unroll
  for (int kt = 0; kt < 4; ++kt) {
    half8t a[4], b[4];
    #pragma unroll
    for (int rt = 0; rt < 4; ++rt)
      a[rt] = *(const half8t*)&NH[(rt * 16 + lr) * US2 + kt * 32 + lk];
    #pragma unroll
    for (int ci = 0; ci < 4; ++ci)
      b[ci] = *(const half8t*)&Wp[(((size_t)kt * 16 + wv * 4 + ci) * 64 + l) * 8];
    #pragma unroll
    for (int rt = 0; rt < 4; ++rt)
      #pragma unroll
      for (int ci = 0; ci < 4; ++ci)
        accp[rt][ci] = __builtin_amdgcn_mfma_f32_16x16x32_f16(a[rt], b[ci], accp[rt][ci], 0, 0, 0);
  }
  #pragma unroll
  for (int rt = 0; rt < 4; ++rt)
    #pragma unroll
    for (int ci = 0; ci < 4; ++ci) {
      int col = (wv * 4 + ci) * 16 + lr;
      float bb = pbias ? pbias[col] : 0.0f;
      #pragma unroll
      for (int rr = 0; rr < 4; ++rr) {
        int row = a0 + rt * 16 + (l >> 4) * 4 + rr;
        if (row < A) PhOut[(size_t)row * 256 + col] = f16u(accp[rt][ci][rr] + bb);
      }
    }
}

// ---------------- tail kernels ---------------------------------------------
__global__ void k_q4b(const float* __restrict__ residue_embed,
                      const float* __restrict__ Wq, const float* __restrict__ bq,
                      const float* __restrict__ bk, const float* __restrict__ bv,
                      float* __restrict__ q4, float* __restrict__ bkv) {
  int i = blockIdx.x * blockDim.x + threadIdx.x;
  if (i < 512) {
    int r = i >> 7, j = i & 127;
    const float* emb = residue_embed + (size_t)r * H;
    float s = bq[j];
    #pragma unroll 4
    for (int k = 0; k < H; ++k) s += emb[k] * Wq[(size_t)k*H + j];
    q4[i] = s;
  } else if (i < 768) {
    int t = i - 512;
    bkv[t] = (t < 128) ? bk[t] : bv[t - 128];
  }
}

// scores[a] = (k[a] . q4[rtype[ridx[a]]]) * H^-0.5   (4 lanes per atom)
__global__ void k_score(const unsigned short* __restrict__ kv,
                        const float* __restrict__ q4,
                        const int* __restrict__ ridx,
                        const int* __restrict__ rtype,
                        float* __restrict__ scores, int A) {
  int t = blockIdx.x * blockDim.x + threadIdx.x;
  int a = t >> 2, qt = t & 3;
  if (a >= A) return;
  const half8t* kr = (const half8t*)(kv + (size_t)a * 256 + qt * 32);
  const float* qrow = q4 + (size_t)rtype[ridx[a]] * H + qt * 32;
  float s = 0.f;
  #pragma unroll
  for (int i = 0; i < 4; ++i) {
    half8t kvv = kr[i];
    #pragma unroll
    for (int j = 0; j < 8; ++j) s += (float)kvv[j] * qrow[i * 8 + j];
  }
  s += __shfl_xor(s, 1);
  s += __shfl_xor(s, 2);
  if (qt == 0) scores[a] = s * 0.08838834764831845f;
}

// per-residue softmax + PV over fp16 kv rows [k(128) | v(128)]
__global__ __launch_bounds__(256) void k_pool(
    const float* __restrict__ scores,
    const unsigned short* __restrict__ kv, const int* __restrict__ starts,
    const int* __restrict__ apr, float* __restrict__ pooled, int N) {
  int r = blockIdx.x * 4 + (threadIdx.x >> 6);
  if (r >= N) return;
  int lane = threadIdx.x & 63;
  int s0 = starts[r], cnt = apr[r];
  float val = (lane < cnt) ? scores[s0 + lane] : -1e30f;
  float mx = val;
  #pragma unroll
  for (int off = 32; off; off >>= 1) mx = fmaxf(mx, __shfl_xor(mx, off));
  float ex = (lane < cnt) ? __expf(val - mx) : 0.0f;
  float sum = ex;
  #pragma unroll
  for (int off = 32; off; off >>= 1) sum += __shfl_xor(sum, off);
  float w = ex * __builtin_amdgcn_rcpf(sum);
  float p0 = 0.f, p1 = 0.f;
  for (int i = 0; i < cnt; ++i) {
    float wi = __shfl(w, i);
    const unsigned short* vr = kv + (size_t)(s0 + i) * 256 + 128;
    p0 += wi * (float)(*(const _Float16*)&vr[lane]);
    p1 += wi * (float)(*(const _Float16*)&vr[64 + lane]);
  }
  pooled[(size_t)r*H + lane] = p0;
  pooled[(size_t)r*H + 64 + lane] = p1;
}

__global__ void k_head(const float* __restrict__ pooled,
                       const float* __restrict__ Wmu, const float* __restrict__ bmu,
                       const float* __restrict__ Wlv, const float* __restrict__ blv,
                       float* __restrict__ out, int N) {
  int i = blockIdx.x * blockDim.x + threadIdx.x;
  if (i >= N * LATD) return;
  int r = i >> 5, j = i & 31;
  const float* p = pooled + (size_t)r * H;
  float smu = 0.f, slv = 0.f;
  #pragma unroll 4
  for (int k = 0; k < H; ++k) {
    float pv = p[k];
    smu += pv * Wmu[(size_t)k*LATD + j];
    slv += pv * Wlv[(size_t)k*LATD + j];
  }
  smu += bmu[j];
  slv += blv[j];
  slv = fminf(fmaxf(slv, -10.0f), 2.0f);
  out[i] = smu;
  out[(size_t)N*LATD + i] = slv;
}

extern "C" void kernel_launch(void* const* d_in, const int* in_sizes, int n_in,
                              void* d_out, int out_size, void* d_ws, size_t ws_size,
                              hipStream_t stream) {
  const float* coords        = (const float*)d_in[0];
  const int*   atype         = (const int*)d_in[1];
  const int*   ridx          = (const int*)d_in[2];
  const int*   rtype         = (const int*)d_in[3];
  const int*   apr           = (const int*)d_in[4];
  const int*   esrc          = (const int*)d_in[5];
  const int*   edst          = (const int*)d_in[6];
  const float* atom_embed    = (const float*)d_in[7];
  const float* residue_embed = (const float*)d_in[8];
  const float* We1 = (const float*)d_in[9];
  const float* be1 = (const float*)d_in[10];
  const float* We2 = (const float*)d_in[11];
  const float* be2 = (const float*)d_in[12];
  const float* Wh1 = (const float*)d_in[13];
  const float* bh1 = (const float*)d_in[14];
  const float* Wh2 = (const float*)d_in[15];
  const float* bh2 = (const float*)d_in[16];
  const float* Wq  = (const float*)d_in[17];
  const float* bq  = (const float*)d_in[18];
  const float* Wk  = (const float*)d_in[19];
  const float* bk  = (const float*)d_in[20];
  const float* Wv  = (const float*)d_in[21];
  const float* bv  = (const float*)d_in[22];
  const float* Wmu = (const float*)d_in[23];
  const float* bmu = (const float*)d_in[24];
  const float* Wlv = (const float*)d_in[25];
  const float* blv = (const float*)d_in[26];

  const int A = in_sizes[1];
  const int N = in_sizes[3];
  const int E = in_sizes[5];

  float* ws     = (float*)d_ws;
  float* h      = ws;                              // A*H f32
  float* agg    = h + (size_t)A * H;               // A*H f32
  float* vbuf   = agg + (size_t)A * H;             // A*H f32 (aliased: Ph, then kv)
  float* dbuf   = vbuf + (size_t)A * H;            // E f32 (later: scores, A<=E)
  float* q4     = dbuf + (size_t)E;                // 4*H
  float* bkv    = q4 + 4 * H;                      // 256
  float* pooled = bkv + 256;                       // N*H
  int*   starts = (int*)(pooled + (size_t)N * H);  // N
  unsigned short* hbuf = (unsigned short*)(starts + N);  // A*H fp16
  int*   eperm  = (int*)(hbuf + (size_t)A * H);    // E
  int*   cnt    = eperm + (size_t)E;               // A
  int*   cursor = cnt + A;                         // A
  int*   bsum   = cursor + A;                      // 64
  unsigned short* wp = (unsigned short*)(bsum + 64);     // WP_TOTAL fp16
  unsigned short* Ph = (unsigned short*)vbuf;      // A*256 fp16 == A*H f32 bytes

  hipMemsetAsync(cnt, 0, (size_t)A * sizeof(int), stream);
  k_pack<<<(WP_TOTAL + 255) / 256, 256, 0, stream>>>(We1, We2, Wh1, Wh2, Wk, Wv, wp);
  k_q4b<<<3, 256, 0, stream>>>(residue_embed, Wq, bq, bk, bv, q4, bkv);
  k_dist<<<(E + 255) / 256, 256, 0, stream>>>(coords, esrc, edst, dbuf, cnt, E);
  // fused: embed-init + starts + agg-zero + layer-0 proj
  k_init_proj<<<(A + 63) / 64, 256, 0, stream>>>(
      atom_embed, residue_embed, atype, ridx, rtype,
      h, hbuf, starts, agg, wp + OFF_PROJ, Ph, A);

  // counting sort of edges by dst (two-level scan; scanC fused into scatter)
  const int nb = (A + 1023) / 1024;
  k_scanA<<<nb, 1024, 0, stream>>>(cnt, cursor, bsum, A);
  k_scanB<<<1, 64, 0, stream>>>(bsum, nb);
  k_scatter<<<(E + 255) / 256, 256, 0, stream>>>(edst, cursor, bsum, eperm, E);

  const int egrid = (E + 63) / 64;
  unsigned short* kv = Ph;  // layer-2 node_proj writes kv into the same region
  for (int l = 0; l < 3; ++l) {
    k_edge_mfma<<<egrid, 256, 0, stream>>>(
        Ph, dbuf, esrc, edst, eperm,
        wp + OFF_RBF16 + (size_t)l * 2048, be1 + (size_t)l * H,
        wp + OFF_W2    + (size_t)l * 16384, be2 + (size_t)l * H, agg, E);
    const unsigned short* Wnext =
        (l < 2) ? (wp + OFF_PROJ + (size_t)(l + 1) * 32768) : (wp + OFF_KV);
    k_node_proj<<<(A + 63) / 64, 256, 0, stream>>>(
        h, hbuf, agg, (l < 2) ? 1 : 0,
        wp + OFF_H1 + (size_t)l * 32768, bh1 + (size_t)l * H,
        wp + OFF_H2 + (size_t)l * 16384, bh2 + (size_t)l * H,
        Wnext, (l < 2) ? nullptr : bkv, Ph, A);
  }

  float* scores = dbuf;     // dbuf dead after last edge; A <= E
  k_score<<<(A * 4 + 255) / 256, 256, 0, stream>>>(kv, q4, ridx, rtype, scores, A);
  k_pool<<<(N + 3) / 4, 256, 0, stream>>>(scores, kv, starts, apr, pooled, N);
  k_head<<<(N * LATD + 255) / 256, 256, 0, stream>>>(pooled, Wmu, bmu, Wlv, blv,
                                                     (float*)d_out, N);
}